// Round 1
// baseline (176.599 us; speedup 1.0000x reference)
//
#include <hip/hip_runtime.h>
#include <stdint.h>

#define D_FEAT 64
#define NEG_INF_BITS 0xFF800000u
#define ENC_NEG_INF  0x007FFFFFu   // order-preserving encoding of -inf
#define NPB 64                      // nodes per bucket (= 1 << BSHIFT)
#define BSHIFT 6
#define BM_BLOCK 512                // bucket_max threads (8 waves)
#define MAXB 2048                   // max buckets (N <= 131072)

// Order-preserving float->uint: enc monotone increasing with float value.
__device__ __forceinline__ unsigned enc_f32(float v) {
    unsigned b = __float_as_uint(v);
    return ((int)b >= 0) ? (b ^ 0x80000000u) : ~b;
}
__device__ __forceinline__ float dec_f32(unsigned u) {
    return (u & 0x80000000u) ? __uint_as_float(u ^ 0x80000000u) : __uint_as_float(~u);
}

// ---------- K1: grid-stride bucket histogram (LDS hist + one global atomic per bucket) ----------
__global__ void count_kernel(const int* __restrict__ dst, int* __restrict__ hist,
                             int E, int B, int aligned4) {
    __shared__ int lh[MAXB];
    for (int i = threadIdx.x; i < B; i += blockDim.x) lh[i] = 0;
    __syncthreads();
    int gid = blockIdx.x * blockDim.x + threadIdx.x;
    int gstride = gridDim.x * blockDim.x;
    int n4 = aligned4 ? (E >> 2) : 0;
    const int4* d4 = (const int4*)dst;
    for (int k = gid; k < n4; k += gstride) {
        int4 d = d4[k];
        atomicAdd(&lh[d.x >> BSHIFT], 1);
        atomicAdd(&lh[d.y >> BSHIFT], 1);
        atomicAdd(&lh[d.z >> BSHIFT], 1);
        atomicAdd(&lh[d.w >> BSHIFT], 1);
    }
    for (int i = (n4 << 2) + gid; i < E; i += gstride)
        atomicAdd(&lh[dst[i] >> BSHIFT], 1);
    __syncthreads();
    for (int i = threadIdx.x; i < B; i += blockDim.x) {
        int c = lh[i];
        if (c) atomicAdd(&hist[i], c);
    }
}

// ---------- K2: single-block exclusive scan (handles B <= 2048 with 1024 threads) ----------
__global__ void scan_kernel(const int* __restrict__ hist, int* __restrict__ bucket_start,
                            int* __restrict__ cursor, int B) {
    __shared__ int lds[MAXB / 2];
    int tid = threadIdx.x;
    int i0 = 2 * tid, i1 = 2 * tid + 1;
    int v0 = (i0 < B) ? hist[i0] : 0;
    int v1 = (i1 < B) ? hist[i1] : 0;
    int s = v0 + v1;
    lds[tid] = s;
    __syncthreads();
    for (int off = 1; off < (MAXB / 2); off <<= 1) {
        int t = (tid >= off) ? lds[tid - off] : 0;
        __syncthreads();
        lds[tid] += t;
        __syncthreads();
    }
    int excl = lds[tid] - s;
    if (i0 < B) { bucket_start[i0] = excl;      cursor[i0] = excl; }
    if (i1 < B) { bucket_start[i1] = excl + v0; cursor[i1] = excl + v0; }
    if (tid == (MAXB / 2) - 1) bucket_start[B] = lds[tid];
}

// ---------- K3: place edges (per-block LDS recount -> atomic range reservation -> LDS cursors) ----------
__global__ void place_kernel(const int* __restrict__ src, const int* __restrict__ dst,
                             int* __restrict__ cursor, unsigned* __restrict__ packed,
                             int E, int Te, int B, int aligned4) {
    __shared__ int lh[MAXB];
    int t = blockIdx.x;
    int beg = t * Te;
    int end = min(E, beg + Te);
    if (beg >= end) return;                      // block-uniform, before any sync
    for (int i = threadIdx.x; i < B; i += blockDim.x) lh[i] = 0;
    __syncthreads();
    int nE = end - beg;
    int n4 = aligned4 ? (nE >> 2) : 0;           // beg is a multiple of 4
    const int4* d4 = (const int4*)(dst + beg);
    for (int k = threadIdx.x; k < n4; k += blockDim.x) {
        int4 d = d4[k];
        atomicAdd(&lh[d.x >> BSHIFT], 1);
        atomicAdd(&lh[d.y >> BSHIFT], 1);
        atomicAdd(&lh[d.z >> BSHIFT], 1);
        atomicAdd(&lh[d.w >> BSHIFT], 1);
    }
    for (int i = beg + (n4 << 2) + threadIdx.x; i < end; i += blockDim.x)
        atomicAdd(&lh[dst[i] >> BSHIFT], 1);
    __syncthreads();
    // reserve this block's range in each non-empty bucket (order within bucket is irrelevant: max)
    for (int i = threadIdx.x; i < B; i += blockDim.x) {
        int c = lh[i];
        lh[i] = c ? atomicAdd(&cursor[i], c) : 0;
    }
    __syncthreads();
    for (int i = beg + threadIdx.x; i < end; i += blockDim.x) {
        int d = dst[i];
        int b = d >> BSHIFT;
        int pos = atomicAdd(&lh[b], 1);
        packed[pos] = (unsigned)src[i] | ((unsigned)(d & (NPB - 1)) << 17);
    }
}

// ---------- K4: per-bucket scatter-max in LDS ----------
__global__ void __launch_bounds__(BM_BLOCK)
bucket_max_kernel(const float* __restrict__ h,
                  const int* __restrict__ bucket_start,
                  const unsigned* __restrict__ packed,
                  float* __restrict__ out, int N) {
    __shared__ unsigned buf[NPB * D_FEAT];   // 16 KB
    int b = blockIdx.x;
    int tid = threadIdx.x;
    int node0 = b << BSHIFT;
    int nvals = (min(NPB, N - node0)) * D_FEAT;

    for (int i = tid; i < NPB * D_FEAT; i += BM_BLOCK) buf[i] = ENC_NEG_INF;
    __syncthreads();

    int beg = bucket_start[b];
    int end = bucket_start[b + 1];
    int wid = tid >> 6;
    int lane = tid & 63;

    for (int base = beg + (wid << 6); base < end; base += BM_BLOCK) {
        int nk = min(64, end - base);
        unsigned p = (lane < nk) ? packed[base + lane] : 0u;
        int j = 0;
        for (; j + 8 <= nk; j += 8) {
            unsigned q[8];
            float v[8];
            #pragma unroll
            for (int k = 0; k < 8; ++k) q[k] = (unsigned)__shfl((int)p, j + k);
            #pragma unroll
            for (int k = 0; k < 8; ++k) v[k] = h[(q[k] & 0x1FFFFu) * D_FEAT + lane];
            #pragma unroll
            for (int k = 0; k < 8; ++k)
                atomicMax(&buf[(q[k] >> 17) * D_FEAT + lane], enc_f32(v[k]));
        }
        for (; j < nk; ++j) {
            unsigned pj = (unsigned)__shfl((int)p, j);
            float v = h[(pj & 0x1FFFFu) * D_FEAT + lane];
            atomicMax(&buf[(pj >> 17) * D_FEAT + lane], enc_f32(v));
        }
    }
    __syncthreads();

    for (int i = tid; i < nvals; i += BM_BLOCK) {
        unsigned u = buf[i];
        out[node0 * D_FEAT + i] = (u == ENC_NEG_INF) ? 0.0f : dec_f32(u);
    }
}

// ---------- fallback: atomic scatter (large-N path) ----------
__global__ void init_out_kernel(uint4* __restrict__ out, int n4) {
    int i = blockIdx.x * blockDim.x + threadIdx.x;
    if (i < n4) {
        uint4 v;
        v.x = NEG_INF_BITS; v.y = NEG_INF_BITS; v.z = NEG_INF_BITS; v.w = NEG_INF_BITS;
        out[i] = v;
    }
}
__global__ void scatter_max_kernel(const float* __restrict__ h, const int* __restrict__ src,
                                   const int* __restrict__ dst, float* __restrict__ out, int E) {
    int gid = blockIdx.x * blockDim.x + threadIdx.x;
    int e = gid >> 6;
    if (e >= E) return;
    int lane = gid & 63;
    float v = h[src[e] * D_FEAT + lane];
    int* addr = (int*)(out + dst[e] * D_FEAT + lane);
    if (v >= 0.0f) atomicMax(addr, __float_as_int(v));
    else           atomicMin((unsigned int*)addr, __float_as_uint(v));
}
__global__ void finalize_kernel(float* __restrict__ out, int n) {
    int i = blockIdx.x * blockDim.x + threadIdx.x;
    if (i < n && __float_as_uint(out[i]) == NEG_INF_BITS) out[i] = 0.0f;
}

// ---------- launch ----------
extern "C" void kernel_launch(void* const* d_in, const int* in_sizes, int n_in,
                              void* d_out, int out_size, void* d_ws, size_t ws_size,
                              hipStream_t stream) {
    const float* h = (const float*)d_in[0];
    const int* edge_index = (const int*)d_in[1];
    int E = in_sizes[1] / 2;                 // edge_index is [2, E] row-major
    const int* src = edge_index;
    const int* dst = edge_index + E;
    float* out = (float*)d_out;
    int N = out_size / D_FEAT;

    int B = (N + NPB - 1) >> BSHIFT;
    size_t need = ((size_t)3 * B + 1 + (size_t)E) * sizeof(int);

    if (N <= (1 << 17) && B <= MAXB && E > 0 && ws_size >= need) {
        int* hist         = (int*)d_ws;              // [B]  (atomic accumulation)
        int* bucket_start = hist + B;                // [B+1]
        int* cursor       = bucket_start + B + 1;    // [B]  (atomic reservation)
        unsigned* packed  = (unsigned*)(cursor + B); // [E]

        int aligned4 = ((((uintptr_t)dst) & 15) == 0) ? 1 : 0;

        hipMemsetAsync(hist, 0, (size_t)B * sizeof(int), stream);

        count_kernel<<<256, 512, 0, stream>>>(dst, hist, E, B, aligned4);
        scan_kernel<<<1, MAXB / 2, 0, stream>>>(hist, bucket_start, cursor, B);
        int Te = ((E + 255) / 256 + 3) & ~3;         // ~E/256 per block, multiple of 4
        int pblocks = (E + Te - 1) / Te;
        place_kernel<<<pblocks, 512, 0, stream>>>(src, dst, cursor, packed, E, Te, B, aligned4);
        bucket_max_kernel<<<B, BM_BLOCK, 0, stream>>>(h, bucket_start, packed, out, N);
    } else {
        int n4 = out_size / 4;
        init_out_kernel<<<(n4 + 255) / 256, 256, 0, stream>>>((uint4*)out, n4);
        long long total = (long long)E * 64;
        scatter_max_kernel<<<(int)((total + 255) / 256), 256, 0, stream>>>(h, src, dst, out, E);
        finalize_kernel<<<(out_size + 255) / 256, 256, 0, stream>>>(out, out_size);
    }
}